// Round 1
// baseline (1129.215 us; speedup 1.0000x reference)
//
#include <hip/hip_runtime.h>

#define NN 50000
#define NE 640000
#define NR 3
#define DH 128

// ---------------- CSR build ----------------
__global__ __launch_bounds__(256) void count_kernel(const int* __restrict__ ei,
                                                    int* __restrict__ deg) {
    int gid = blockIdx.x * 256 + threadIdx.x;
    if (gid >= NR * NE) return;
    int r = gid / NE, e = gid - r * NE;
    int dst = ei[r * 2 * NE + NE + e];
    atomicAdd(&deg[r * NN + dst], 1);
}

__global__ __launch_bounds__(1024) void scan_kernel(const int* __restrict__ deg,
                                                    int* __restrict__ offs,
                                                    int* __restrict__ cur) {
    const int r = blockIdx.x;      // relation
    const int t = threadIdx.x;     // 1024 threads
    const int CH = (NN + 1023) / 1024;  // 49
    int lo = t * CH; int hi = lo + CH;
    if (hi > NN) hi = NN;
    if (lo > NN) lo = NN;
    int s = 0;
    for (int i = lo; i < hi; ++i) s += deg[r * NN + i];
    int lane = t & 63, w = t >> 6;
    int v = s;
#pragma unroll
    for (int d = 1; d < 64; d <<= 1) {
        int u = __shfl_up(v, d);
        if (lane >= d) v += u;
    }
    __shared__ int wsum_s[16];
    if (lane == 63) wsum_s[w] = v;
    __syncthreads();
    if (t < 16) {
        int wv = wsum_s[t];
#pragma unroll
        for (int d = 1; d < 16; d <<= 1) {
            int u = __shfl_up(wv, d);
            if (t >= d) wv += u;
        }
        wsum_s[t] = wv;  // inclusive wave sums
    }
    __syncthreads();
    int ex = (w == 0 ? 0 : wsum_s[w - 1]) + (v - s);  // exclusive prefix for thread
    int run = ex;
    for (int i = lo; i < hi; ++i) {
        int d = deg[r * NN + i];
        offs[r * NN + i] = run;
        cur[r * NN + i] = run;
        run += d;
    }
}

__global__ __launch_bounds__(256) void fill_kernel(const int* __restrict__ ei,
                                                   int* __restrict__ cur,
                                                   int* __restrict__ csr) {
    int gid = blockIdx.x * 256 + threadIdx.x;
    if (gid >= NR * NE) return;
    int r = gid / NE, e = gid - r * NE;
    int src = ei[r * 2 * NE + e];
    int dst = ei[r * 2 * NE + NE + e];
    int pos = atomicAdd(&cur[r * NN + dst], 1);
    csr[r * NE + pos] = src;
}

// ---------------- weight pre-sum: Wr_sum[l] = sum_r W_root[l][r], b_sum[l] = sum_r b[l][r]
__global__ __launch_bounds__(256) void wsum_kernel(const float* __restrict__ Wr,
                                                   const float* __restrict__ bc,
                                                   float* __restrict__ Wrs,
                                                   float* __restrict__ bsum) {
    int gid = blockIdx.x * 256 + threadIdx.x;
    const int WS = 2 * DH * DH;  // 32768
    if (gid < WS) {
        int l = gid >> 14, ij = gid & 16383;
        const float* base = Wr + (size_t)l * 3 * 16384;
        Wrs[gid] = base[ij] + base[16384 + ij] + base[2 * 16384 + ij];
    } else if (gid < WS + 2 * DH) {
        int g = gid - WS;
        int l = g >> 7, j = g & 127;
        const float* bb = bc + l * 3 * DH;
        bsum[g] = bb[j] + bb[DH + j] + bb[2 * DH + j];
    }
}

// ---------------- fused layer: aggregate (CSR pull) + K=512 GEMM (+ final linear)
// Block: 256 threads, 64 rows x 128 cols output tile. A staged transposed in LDS.
template <bool LAST>
__global__ __launch_bounds__(256) void layer_kernel(
    const float* __restrict__ h_in, float* __restrict__ h_out,
    const int* __restrict__ csr, const int* __restrict__ offs,
    const int* __restrict__ deg,
    const float* __restrict__ Wn,    // [3][128][128] this layer
    const float* __restrict__ Wrs,   // [128][128]
    const float* __restrict__ bsum,  // [128]
    const float* __restrict__ linW,  // [128][32] (LAST only)
    const float* __restrict__ linb)  // [32]     (LAST only)
{
    __shared__ float At[DH][65];  // A^T tile: At[k][row], stride-65 pad
    __shared__ float Bs[32][DH];  // weight K-chunk

    const int t = threadIdx.x;
    const int lane = t & 63, wave = t >> 6;
    const int tx = t & 15, ty = t >> 4;
    const int row0 = blockIdx.x * 64;

    // acc[m][j]: rows row0 + ty*4 + m; cols tx*4+j (j<4), 64+tx*4+(j-4) (j>=4)
    float acc[4][8];
#pragma unroll
    for (int j = 0; j < 4; ++j) {
        float b0 = bsum[tx * 4 + j], b1 = bsum[64 + tx * 4 + j];
#pragma unroll
        for (int m = 0; m < 4; ++m) {
            acc[m][j] = b0;
            acc[m][j + 4] = b1;
        }
    }

    for (int s = 0; s < 4; ++s) {
        __syncthreads();  // previous segment's FMA reads of At done
        // ---- stage A^T: segment s<3 = mean_s (CSR pull), s==3 = h row ----
        for (int r = wave; r < 64; r += 4) {
            int node = row0 + r;
            float s0 = 0.f, s1 = 0.f;
            if (node < NN) {
                if (s < NR) {
                    int base = offs[s * NN + node];
                    int d = deg[s * NN + node];
                    const int* lst = csr + s * NE + base;
                    int e = 0;
                    for (; e + 4 <= d; e += 4) {  // unroll-by-4: 4 gathers in flight
                        int i0 = lst[e], i1 = lst[e + 1], i2 = lst[e + 2], i3 = lst[e + 3];
                        float2 v0 = *(const float2*)(h_in + i0 * DH + lane * 2);
                        float2 v1 = *(const float2*)(h_in + i1 * DH + lane * 2);
                        float2 v2 = *(const float2*)(h_in + i2 * DH + lane * 2);
                        float2 v3 = *(const float2*)(h_in + i3 * DH + lane * 2);
                        s0 += v0.x + v1.x + v2.x + v3.x;
                        s1 += v0.y + v1.y + v2.y + v3.y;
                    }
                    for (; e < d; ++e) {
                        int i0 = lst[e];
                        float2 v0 = *(const float2*)(h_in + i0 * DH + lane * 2);
                        s0 += v0.x;
                        s1 += v0.y;
                    }
                    float inv = 1.f / fmaxf((float)d, 1.f);
                    s0 *= inv;
                    s1 *= inv;
                } else {
                    float2 v = *(const float2*)(h_in + node * DH + lane * 2);
                    s0 = v.x;
                    s1 = v.y;
                }
            }
            At[lane * 2][r] = s0;
            At[lane * 2 + 1][r] = s1;
        }
        const float* W = (s < NR) ? (Wn + s * DH * DH) : Wrs;
        for (int kk = 0; kk < 4; ++kk) {
            __syncthreads();  // Bs safe to overwrite; At writes visible after next sync
            const float4* wv = (const float4*)(W + kk * 32 * DH);
            float4* bsv = (float4*)&Bs[0][0];
#pragma unroll
            for (int q = 0; q < 4; ++q) bsv[t * 4 + q] = wv[t * 4 + q];
            __syncthreads();
#pragma unroll
            for (int k = 0; k < 32; ++k) {
                float a[4];
#pragma unroll
                for (int m = 0; m < 4; ++m) a[m] = At[kk * 32 + k][ty * 4 + m];
                float4 b0 = *(const float4*)&Bs[k][tx * 4];
                float4 b1 = *(const float4*)&Bs[k][64 + tx * 4];
                float b[8] = {b0.x, b0.y, b0.z, b0.w, b1.x, b1.y, b1.z, b1.w};
#pragma unroll
                for (int m = 0; m < 4; ++m)
#pragma unroll
                    for (int j = 0; j < 8; ++j) acc[m][j] += a[m] * b[j];
            }
        }
    }

    if constexpr (!LAST) {
#pragma unroll
        for (int m = 0; m < 4; ++m) {
            int node = row0 + ty * 4 + m;
            if (node < NN) {
                float4 o0 = make_float4(fmaxf(acc[m][0], 0.f), fmaxf(acc[m][1], 0.f),
                                        fmaxf(acc[m][2], 0.f), fmaxf(acc[m][3], 0.f));
                float4 o1 = make_float4(fmaxf(acc[m][4], 0.f), fmaxf(acc[m][5], 0.f),
                                        fmaxf(acc[m][6], 0.f), fmaxf(acc[m][7], 0.f));
                *(float4*)(h_out + (size_t)node * DH + tx * 4) = o0;
                *(float4*)(h_out + (size_t)node * DH + 64 + tx * 4) = o1;
            }
        }
    } else {
        // h2 = relu(acc) -> At (transposed), then out = h2 @ linW + linb
        __syncthreads();  // all FMA reads of At/Bs done
#pragma unroll
        for (int m = 0; m < 4; ++m) {
#pragma unroll
            for (int j = 0; j < 4; ++j) {
                At[tx * 4 + j][ty * 4 + m] = fmaxf(acc[m][j], 0.f);
                At[64 + tx * 4 + j][ty * 4 + m] = fmaxf(acc[m][j + 4], 0.f);
            }
        }
        float* bsf = &Bs[0][0];
        const float4* lwv = (const float4*)linW;  // 128x32 = 4096 floats
        float4* bsv = (float4*)bsf;
#pragma unroll
        for (int q = 0; q < 4; ++q) bsv[t * 4 + q] = lwv[t * 4 + q];
        __syncthreads();
        int r2 = t >> 2;          // 0..63 row
        int c0 = (t & 3) * 8;     // 0,8,16,24
        float o[8];
#pragma unroll
        for (int j = 0; j < 8; ++j) o[j] = linb[c0 + j];
        for (int k = 0; k < DH; ++k) {
            float hv = At[k][r2];
#pragma unroll
            for (int j = 0; j < 8; ++j) o[j] += hv * bsf[k * 32 + c0 + j];
        }
        int node = row0 + r2;
        if (node < NN) {
            *(float4*)(h_out + (size_t)node * 32 + c0) = make_float4(o[0], o[1], o[2], o[3]);
            *(float4*)(h_out + (size_t)node * 32 + c0 + 4) = make_float4(o[4], o[5], o[6], o[7]);
        }
    }
}

extern "C" void kernel_launch(void* const* d_in, const int* in_sizes, int n_in,
                              void* d_out, int out_size, void* d_ws, size_t ws_size,
                              hipStream_t stream) {
    const float* x = (const float*)d_in[0];     // [50000][128]
    const int* ei = (const int*)d_in[1];        // [3][2][640000]
    const float* Wn = (const float*)d_in[2];    // [2][3][128][128]
    const float* Wr = (const float*)d_in[3];    // [2][3][128][128]
    const float* bc = (const float*)d_in[4];    // [2][3][128]
    const float* linW = (const float*)d_in[5];  // [128][32]
    const float* linb = (const float*)d_in[6];  // [32]
    float* out = (float*)d_out;                 // [50000][32]

    char* p = (char*)d_ws;
    int* deg = (int*)p;    p += (size_t)NR * NN * 4;
    int* offs = (int*)p;   p += (size_t)NR * NN * 4;
    int* cur = (int*)p;    p += (size_t)NR * NN * 4;
    int* csr = (int*)p;    p += (size_t)NR * NE * 4;
    float* Wrs = (float*)p;  p += (size_t)2 * DH * DH * 4;
    float* bsum = (float*)p; p += (size_t)2 * DH * 4;
    float* hbuf = (float*)p; p += (size_t)NN * DH * 4;  // total ~35.2 MB

    hipMemsetAsync(deg, 0, (size_t)NR * NN * 4, stream);

    int eb = (NR * NE + 255) / 256;  // 7500
    count_kernel<<<eb, 256, 0, stream>>>(ei, deg);
    scan_kernel<<<NR, 1024, 0, stream>>>(deg, offs, cur);
    fill_kernel<<<eb, 256, 0, stream>>>(ei, cur, csr);
    wsum_kernel<<<(2 * (DH * DH + DH) + 255) / 256, 256, 0, stream>>>(Wr, bc, Wrs, bsum);

    int lb = (NN + 63) / 64;  // 782
    layer_kernel<false><<<lb, 256, 0, stream>>>(x, hbuf, csr, offs, deg,
                                                Wn, Wrs, bsum, nullptr, nullptr);
    layer_kernel<true><<<lb, 256, 0, stream>>>(hbuf, out, csr, offs, deg,
                                               Wn + (size_t)3 * DH * DH, Wrs + DH * DH,
                                               bsum + DH, linW, linb);
}

// Round 2
// 800.431 us; speedup vs baseline: 1.4108x; 1.4108x over previous
//
#include <hip/hip_runtime.h>

#define NN 50000
#define NE 640000
#define NR 3
#define DH 128

__device__ __forceinline__ float bf2f(uint u) { return __uint_as_float(u << 16); }
__device__ __forceinline__ uint f2bf(float f) {
    uint u = __float_as_uint(f);
    u += 0x7fff + ((u >> 16) & 1);  // round-to-nearest-even
    return u >> 16;
}
__device__ __forceinline__ uint pack2(float a, float b) { return f2bf(a) | (f2bf(b) << 16); }

// ---------------- CSR build ----------------
__global__ __launch_bounds__(256) void count_kernel(const int* __restrict__ ei,
                                                    int* __restrict__ deg) {
    int gid = blockIdx.x * 256 + threadIdx.x;
    if (gid >= NR * NE) return;
    int r = gid / NE, e = gid - r * NE;
    int dst = ei[r * 2 * NE + NE + e];
    atomicAdd(&deg[r * NN + dst], 1);
}

__global__ __launch_bounds__(1024) void scan_kernel(const int* __restrict__ deg,
                                                    int* __restrict__ offs,
                                                    int* __restrict__ cur) {
    const int r = blockIdx.x;
    const int t = threadIdx.x;
    const int CH = (NN + 1023) / 1024;  // 49
    int lo = t * CH; int hi = lo + CH;
    if (hi > NN) hi = NN;
    if (lo > NN) lo = NN;
    int s = 0;
    for (int i = lo; i < hi; ++i) s += deg[r * NN + i];
    int lane = t & 63, w = t >> 6;
    int v = s;
#pragma unroll
    for (int d = 1; d < 64; d <<= 1) {
        int u = __shfl_up(v, d);
        if (lane >= d) v += u;
    }
    __shared__ int wsum_s[16];
    if (lane == 63) wsum_s[w] = v;
    __syncthreads();
    if (t < 16) {
        int wv = wsum_s[t];
#pragma unroll
        for (int d = 1; d < 16; d <<= 1) {
            int u = __shfl_up(wv, d);
            if (t >= d) wv += u;
        }
        wsum_s[t] = wv;
    }
    __syncthreads();
    int ex = (w == 0 ? 0 : wsum_s[w - 1]) + (v - s);
    int run = ex;
    for (int i = lo; i < hi; ++i) {
        int d = deg[r * NN + i];
        offs[r * NN + i] = run;
        cur[r * NN + i] = run;
        run += d;
    }
}

__global__ __launch_bounds__(256) void fill_kernel(const int* __restrict__ ei,
                                                   int* __restrict__ cur,
                                                   int* __restrict__ csr) {
    int gid = blockIdx.x * 256 + threadIdx.x;
    if (gid >= NR * NE) return;
    int r = gid / NE, e = gid - r * NE;
    int src = ei[r * 2 * NE + e];
    int dst = ei[r * 2 * NE + NE + e];
    int pos = atomicAdd(&cur[r * NN + dst], 1);
    csr[r * NE + pos] = src;
}

// ---------------- weight pre-sum ----------------
__global__ __launch_bounds__(256) void wsum_kernel(const float* __restrict__ Wr,
                                                   const float* __restrict__ bc,
                                                   float* __restrict__ Wrs,
                                                   float* __restrict__ bsum) {
    int gid = blockIdx.x * 256 + threadIdx.x;
    const int WS = 2 * DH * DH;
    if (gid < WS) {
        int l = gid >> 14, ij = gid & 16383;
        const float* base = Wr + (size_t)l * 3 * 16384;
        Wrs[gid] = base[ij] + base[16384 + ij] + base[2 * 16384 + ij];
    } else if (gid < WS + 2 * DH) {
        int g = gid - WS;
        int l = g >> 7, j = g & 127;
        const float* bb = bc + l * 3 * DH;
        bsum[g] = bb[j] + bb[DH + j] + bb[2 * DH + j];
    }
}

// ---------------- fp32 -> bf16 table conversion ----------------
__global__ __launch_bounds__(256) void conv_kernel(const float* __restrict__ x,
                                                   ushort* __restrict__ xb) {
    int gid = blockIdx.x * 256 + threadIdx.x;
    if (gid >= NN * DH / 4) return;
    float4 v = ((const float4*)x)[gid];
    uint2 o;
    o.x = pack2(v.x, v.y);
    o.y = pack2(v.z, v.w);
    ((uint2*)xb)[gid] = o;
}

// ---------------- aggregation: one wave per (rel,node), bf16 gather, fp32 accum
__global__ __launch_bounds__(256) void aggr_kernel(const ushort* __restrict__ tb,
                                                   ushort* __restrict__ mean_b,
                                                   const int* __restrict__ csr,
                                                   const int* __restrict__ offs,
                                                   const int* __restrict__ deg) {
    int wid = (blockIdx.x * 256 + threadIdx.x) >> 6;
    wid = __builtin_amdgcn_readfirstlane(wid);  // wave-uniform -> SGPR (scalar idx loads)
    int lane = threadIdx.x & 63;
    if (wid >= NR * NN) return;
    int r = wid / NN;
    int base = offs[wid];
    int d = deg[wid];
    const int* lst = csr + r * NE + base;
    float s0 = 0.f, s1 = 0.f;
    int e = 0;
    for (; e + 8 <= d; e += 8) {  // 8 gathers in flight per wave
        uint v[8];
#pragma unroll
        for (int q = 0; q < 8; ++q) {
            int idx = lst[e + q];
            v[q] = *(const uint*)(tb + (size_t)idx * DH + lane * 2);
        }
#pragma unroll
        for (int q = 0; q < 8; ++q) {
            s0 += bf2f(v[q] & 0xffffu);
            s1 += bf2f(v[q] >> 16);
        }
    }
    for (; e < d; ++e) {
        int idx = lst[e];
        uint v = *(const uint*)(tb + (size_t)idx * DH + lane * 2);
        s0 += bf2f(v & 0xffffu);
        s1 += bf2f(v >> 16);
    }
    float inv = 1.f / fmaxf((float)d, 1.f);
    *(uint*)(mean_b + (size_t)wid * DH + lane * 2) = pack2(s0 * inv, s1 * inv);
}

// ---------------- GEMM: [mean0|mean1|mean2|h] (bf16) @ W (fp32), 64x128 tile, K=512
template <bool LAST>
__global__ __launch_bounds__(256) void gemm_kernel(
    const ushort* __restrict__ tb,      // bf16 node table [NN][128] (root segment)
    const ushort* __restrict__ mean_b,  // bf16 means [3][NN][128]
    void* __restrict__ h_out,           // LAST ? float* [NN][32] : ushort* [NN][128]
    const float* __restrict__ Wn,       // [3][128][128] this layer
    const float* __restrict__ Wrs,      // [128][128]
    const float* __restrict__ bsum,     // [128]
    const float* __restrict__ linW,     // [128][32] (LAST)
    const float* __restrict__ linb)     // [32]     (LAST)
{
    __shared__ float At[DH][65];
    __shared__ float Bs[32][DH];

    const int t = threadIdx.x;
    const int lane = t & 63, wave = t >> 6;
    const int tx = t & 15, ty = t >> 4;
    const int row0 = blockIdx.x * 64;

    float acc[4][8];
#pragma unroll
    for (int j = 0; j < 4; ++j) {
        float b0 = bsum[tx * 4 + j], b1 = bsum[64 + tx * 4 + j];
#pragma unroll
        for (int m = 0; m < 4; ++m) {
            acc[m][j] = b0;
            acc[m][j + 4] = b1;
        }
    }

    for (int s = 0; s < 4; ++s) {
        __syncthreads();
        for (int rr = wave; rr < 64; rr += 4) {
            int node = row0 + rr;
            float s0 = 0.f, s1 = 0.f;
            if (node < NN) {
                const ushort* src = (s < NR) ? (mean_b + ((size_t)s * NN + node) * DH)
                                             : (tb + (size_t)node * DH);
                uint v = *(const uint*)(src + lane * 2);
                s0 = bf2f(v & 0xffffu);
                s1 = bf2f(v >> 16);
            }
            At[lane * 2][rr] = s0;
            At[lane * 2 + 1][rr] = s1;
        }
        const float* W = (s < NR) ? (Wn + s * DH * DH) : Wrs;
        for (int kk = 0; kk < 4; ++kk) {
            __syncthreads();
            const float4* wv = (const float4*)(W + kk * 32 * DH);
            float4* bsv = (float4*)&Bs[0][0];
#pragma unroll
            for (int q = 0; q < 4; ++q) bsv[t * 4 + q] = wv[t * 4 + q];
            __syncthreads();
#pragma unroll
            for (int k = 0; k < 32; ++k) {
                float a[4];
#pragma unroll
                for (int m = 0; m < 4; ++m) a[m] = At[kk * 32 + k][ty * 4 + m];
                float4 b0 = *(const float4*)&Bs[k][tx * 4];
                float4 b1 = *(const float4*)&Bs[k][64 + tx * 4];
                float b[8] = {b0.x, b0.y, b0.z, b0.w, b1.x, b1.y, b1.z, b1.w};
#pragma unroll
                for (int m = 0; m < 4; ++m)
#pragma unroll
                    for (int j = 0; j < 8; ++j) acc[m][j] += a[m] * b[j];
            }
        }
    }

    if constexpr (!LAST) {
        ushort* hb = (ushort*)h_out;
#pragma unroll
        for (int m = 0; m < 4; ++m) {
            int node = row0 + ty * 4 + m;
            if (node < NN) {
                uint2 o0, o1;
                o0.x = pack2(fmaxf(acc[m][0], 0.f), fmaxf(acc[m][1], 0.f));
                o0.y = pack2(fmaxf(acc[m][2], 0.f), fmaxf(acc[m][3], 0.f));
                o1.x = pack2(fmaxf(acc[m][4], 0.f), fmaxf(acc[m][5], 0.f));
                o1.y = pack2(fmaxf(acc[m][6], 0.f), fmaxf(acc[m][7], 0.f));
                *(uint2*)(hb + (size_t)node * DH + tx * 4) = o0;
                *(uint2*)(hb + (size_t)node * DH + 64 + tx * 4) = o1;
            }
        }
    } else {
        float* outp = (float*)h_out;
        __syncthreads();
#pragma unroll
        for (int m = 0; m < 4; ++m) {
#pragma unroll
            for (int j = 0; j < 4; ++j) {
                At[tx * 4 + j][ty * 4 + m] = fmaxf(acc[m][j], 0.f);
                At[64 + tx * 4 + j][ty * 4 + m] = fmaxf(acc[m][j + 4], 0.f);
            }
        }
        float* bsf = &Bs[0][0];
        const float4* lwv = (const float4*)linW;
        float4* bsv = (float4*)bsf;
#pragma unroll
        for (int q = 0; q < 4; ++q) bsv[t * 4 + q] = lwv[t * 4 + q];
        __syncthreads();
        int r2 = t >> 2;
        int c0 = (t & 3) * 8;
        float o[8];
#pragma unroll
        for (int j = 0; j < 8; ++j) o[j] = linb[c0 + j];
        for (int k = 0; k < DH; ++k) {
            float hv = At[k][r2];
#pragma unroll
            for (int j = 0; j < 8; ++j) o[j] += hv * bsf[k * 32 + c0 + j];
        }
        int node = row0 + r2;
        if (node < NN) {
            *(float4*)(outp + (size_t)node * 32 + c0) = make_float4(o[0], o[1], o[2], o[3]);
            *(float4*)(outp + (size_t)node * 32 + c0 + 4) = make_float4(o[4], o[5], o[6], o[7]);
        }
    }
}

extern "C" void kernel_launch(void* const* d_in, const int* in_sizes, int n_in,
                              void* d_out, int out_size, void* d_ws, size_t ws_size,
                              hipStream_t stream) {
    const float* x = (const float*)d_in[0];
    const int* ei = (const int*)d_in[1];
    const float* Wn = (const float*)d_in[2];
    const float* Wr = (const float*)d_in[3];
    const float* bc = (const float*)d_in[4];
    const float* linW = (const float*)d_in[5];
    const float* linb = (const float*)d_in[6];
    float* out = (float*)d_out;

    char* p = (char*)d_ws;
    int* deg = (int*)p;      p += (size_t)NR * NN * 4;
    int* offs = (int*)p;     p += (size_t)NR * NN * 4;
    int* cur = (int*)p;      p += (size_t)NR * NN * 4;
    int* csr = (int*)p;      p += (size_t)NR * NE * 4;
    float* Wrs = (float*)p;  p += (size_t)2 * DH * DH * 4;
    float* bsum = (float*)p; p += 4096;  // keep 16B alignment, room for 256 floats
    ushort* xb = (ushort*)p;  p += (size_t)NN * DH * 2;
    ushort* h1b = (ushort*)p; p += (size_t)NN * DH * 2;
    ushort* mean_b = (ushort*)p; p += (size_t)NR * NN * DH * 2;  // total ~74 MB

    hipMemsetAsync(deg, 0, (size_t)NR * NN * 4, stream);

    int eb = (NR * NE + 255) / 256;
    count_kernel<<<eb, 256, 0, stream>>>(ei, deg);
    scan_kernel<<<NR, 1024, 0, stream>>>(deg, offs, cur);
    fill_kernel<<<eb, 256, 0, stream>>>(ei, cur, csr);
    wsum_kernel<<<(2 * (DH * DH + DH) + 255) / 256, 256, 0, stream>>>(Wr, bc, Wrs, bsum);
    conv_kernel<<<(NN * DH / 4 + 255) / 256, 256, 0, stream>>>(x, xb);

    int ab = (NR * NN + 3) / 4;   // waves->blocks: 4 waves/block
    ab = (ab + 0);                // 37500 blocks
    int lb = (NN + 63) / 64;      // 782 blocks

    // layer 1
    aggr_kernel<<<(NR * NN * 64 + 255) / 256, 256, 0, stream>>>(xb, mean_b, csr, offs, deg);
    gemm_kernel<false><<<lb, 256, 0, stream>>>(xb, mean_b, h1b, Wn, Wrs, bsum,
                                               nullptr, nullptr);
    // layer 2
    aggr_kernel<<<(NR * NN * 64 + 255) / 256, 256, 0, stream>>>(h1b, mean_b, csr, offs, deg);
    gemm_kernel<true><<<lb, 256, 0, stream>>>(h1b, mean_b, out,
                                              Wn + (size_t)3 * DH * DH, Wrs + DH * DH,
                                              bsum + DH, linW, linb);
}

// Round 3
// 531.092 us; speedup vs baseline: 2.1262x; 1.5071x over previous
//
#include <hip/hip_runtime.h>

#define NN 50000
#define NE 640000
#define NR 3
#define DH 128

typedef __attribute__((ext_vector_type(8))) short short8;
typedef __attribute__((ext_vector_type(4))) float f32x4;

__device__ __forceinline__ float bf2f(uint u) { return __uint_as_float(u << 16); }
__device__ __forceinline__ uint f2bf(float f) {
    uint u = __float_as_uint(f);
    u += 0x7fff + ((u >> 16) & 1);  // round-to-nearest-even
    return u >> 16;
}
__device__ __forceinline__ uint pack2(float a, float b) { return f2bf(a) | (f2bf(b) << 16); }

// ---------------- CSR build ----------------
__global__ __launch_bounds__(256) void count_kernel(const int* __restrict__ ei,
                                                    int* __restrict__ deg) {
    int gid = blockIdx.x * 256 + threadIdx.x;
    if (gid >= NR * NE) return;
    int r = gid / NE, e = gid - r * NE;
    int dst = ei[r * 2 * NE + NE + e];
    atomicAdd(&deg[r * NN + dst], 1);
}

__global__ __launch_bounds__(1024) void scan_kernel(const int* __restrict__ deg,
                                                    int* __restrict__ offs,
                                                    int* __restrict__ cur) {
    const int r = blockIdx.x;
    const int t = threadIdx.x;
    const int CH = (NN + 1023) / 1024;  // 49
    int lo = t * CH; int hi = lo + CH;
    if (hi > NN) hi = NN;
    if (lo > NN) lo = NN;
    int s = 0;
    for (int i = lo; i < hi; ++i) s += deg[r * NN + i];
    int lane = t & 63, w = t >> 6;
    int v = s;
#pragma unroll
    for (int d = 1; d < 64; d <<= 1) {
        int u = __shfl_up(v, d);
        if (lane >= d) v += u;
    }
    __shared__ int wsum_s[16];
    if (lane == 63) wsum_s[w] = v;
    __syncthreads();
    if (t < 16) {
        int wv = wsum_s[t];
#pragma unroll
        for (int d = 1; d < 16; d <<= 1) {
            int u = __shfl_up(wv, d);
            if (t >= d) wv += u;
        }
        wsum_s[t] = wv;
    }
    __syncthreads();
    int ex = (w == 0 ? 0 : wsum_s[w - 1]) + (v - s);
    int run = ex;
    for (int i = lo; i < hi; ++i) {
        int d = deg[r * NN + i];
        offs[r * NN + i] = run;
        cur[r * NN + i] = run;
        run += d;
    }
}

__global__ __launch_bounds__(256) void fill_kernel(const int* __restrict__ ei,
                                                   int* __restrict__ cur,
                                                   int* __restrict__ csr) {
    int gid = blockIdx.x * 256 + threadIdx.x;
    if (gid >= NR * NE) return;
    int r = gid / NE, e = gid - r * NE;
    int src = ei[r * 2 * NE + e];
    int dst = ei[r * 2 * NE + NE + e];
    int pos = atomicAdd(&cur[r * NN + dst], 1);
    csr[r * NE + pos] = src;
}

// ---------------- weight prep: pack W into MFMA B-fragment layout, hi/lo bf16 split
// Fragment f (0..255): layer=f>>7, seg=(f>>5)&3, kc=(f>>3)&3, nb=f&7.
// Fragments 256..263: linW, kc=(f-256)>>1, nb=(f-256)&1.
// Storage: Wpack[f*1024 + {0=hi,512=lo} + lane*8 + e] (ushort)
__global__ __launch_bounds__(256) void prep_kernel(const float* __restrict__ Wn,
                                                   const float* __restrict__ Wr,
                                                   const float* __restrict__ linW,
                                                   ushort* __restrict__ Wpack) {
    int tid = blockIdx.x * 256 + threadIdx.x;
    if (tid >= 264 * 64) return;
    int f = tid >> 6, lane = tid & 63;
    int l15 = lane & 15, l4 = lane >> 4;
    ushort hi8[8], lo8[8];
    if (f < 256) {
        int layer = f >> 7, seg = (f >> 5) & 3, kc = (f >> 3) & 3, nb = f & 7;
        int col = nb * 16 + l15;
        int kb = kc * 32 + l4 * 8;
#pragma unroll
        for (int e = 0; e < 8; ++e) {
            int k = kb + e;
            float v;
            if (seg < 3) {
                v = Wn[(((size_t)layer * 3 + seg) * 128 + k) * 128 + col];
            } else {
                const float* base = Wr + (size_t)layer * 3 * 16384;
                v = base[k * 128 + col] + base[16384 + k * 128 + col] +
                    base[32768 + k * 128 + col];
            }
            uint h = f2bf(v);
            float rem = v - bf2f(h);
            hi8[e] = (ushort)h;
            lo8[e] = (ushort)f2bf(rem);
        }
    } else {
        int g = f - 256;
        int kc = g >> 1, nb = g & 1;
        int col = nb * 16 + l15;
        int kb = kc * 32 + l4 * 8;
#pragma unroll
        for (int e = 0; e < 8; ++e) {
            float v = linW[(kb + e) * 32 + col];
            uint h = f2bf(v);
            float rem = v - bf2f(h);
            hi8[e] = (ushort)h;
            lo8[e] = (ushort)f2bf(rem);
        }
    }
    *(short8*)(Wpack + (size_t)f * 1024 + lane * 8) = *(short8*)hi8;
    *(short8*)(Wpack + (size_t)f * 1024 + 512 + lane * 8) = *(short8*)lo8;
}

// bsum[l][j] = sum_r b_conv[l][r][j] (fp32)
__global__ __launch_bounds__(256) void bias_kernel(const float* __restrict__ bc,
                                                   float* __restrict__ bsum) {
    int tid = threadIdx.x;  // 256 = 2 layers x 128
    int l = tid >> 7, j = tid & 127;
    const float* bb = bc + l * 3 * DH;
    bsum[tid] = bb[j] + bb[DH + j] + bb[2 * DH + j];
}

// ---------------- fp32 -> bf16 table conversion ----------------
__global__ __launch_bounds__(256) void conv_kernel(const float* __restrict__ x,
                                                   ushort* __restrict__ xb) {
    int gid = blockIdx.x * 256 + threadIdx.x;
    if (gid >= NN * DH / 4) return;
    float4 v = ((const float4*)x)[gid];
    uint2 o;
    o.x = pack2(v.x, v.y);
    o.y = pack2(v.z, v.w);
    ((uint2*)xb)[gid] = o;
}

// ---------------- aggregation: one wave per (rel,node), bf16 gather, fp32 accum
__global__ __launch_bounds__(256) void aggr_kernel(const ushort* __restrict__ tb,
                                                   ushort* __restrict__ mean_b,
                                                   const int* __restrict__ csr,
                                                   const int* __restrict__ offs,
                                                   const int* __restrict__ deg) {
    int wid = (blockIdx.x * 256 + threadIdx.x) >> 6;
    wid = __builtin_amdgcn_readfirstlane(wid);
    int lane = threadIdx.x & 63;
    if (wid >= NR * NN) return;
    int r = wid / NN;
    int base = offs[wid];
    int d = deg[wid];
    const int* lst = csr + r * NE + base;
    float s0 = 0.f, s1 = 0.f;
    int e = 0;
    for (; e + 8 <= d; e += 8) {
        uint v[8];
#pragma unroll
        for (int q = 0; q < 8; ++q) {
            int idx = lst[e + q];
            v[q] = *(const uint*)(tb + (size_t)idx * DH + lane * 2);
        }
#pragma unroll
        for (int q = 0; q < 8; ++q) {
            s0 += bf2f(v[q] & 0xffffu);
            s1 += bf2f(v[q] >> 16);
        }
    }
    for (; e < d; ++e) {
        int idx = lst[e];
        uint v = *(const uint*)(tb + (size_t)idx * DH + lane * 2);
        s0 += bf2f(v & 0xffffu);
        s1 += bf2f(v >> 16);
    }
    float inv = 1.f / fmaxf((float)d, 1.f);
    *(uint*)(mean_b + (size_t)wid * DH + lane * 2) = pack2(s0 * inv, s1 * inv);
}

// ---------------- MFMA GEMM: [mean0|mean1|mean2|h](bf16) @ W, 64x128 tile
// Swapped-operand mfma => lane holds (node=lane&15-based row, 4 consecutive out cols).
template <bool LAST>
__global__ __launch_bounds__(256) void gemm_mfma(
    const ushort* __restrict__ tb,      // [NN][128] bf16 (root segment)
    const ushort* __restrict__ mean_b,  // [3][NN][128] bf16
    void* __restrict__ h_out,           // LAST ? float*[NN][32] : ushort*[NN][128]
    const ushort* __restrict__ Wp,      // this layer: [4 seg][4 kc][8 nb][2][64][8]
    const float* __restrict__ bsum,     // [128] fp32, this layer
    const ushort* __restrict__ lWp,     // [4 kc][2 nb][2][64][8] (LAST)
    const float* __restrict__ linb)     // [32] (LAST)
{
    __shared__ ushort As[64][136];  // 272 B row stride: 16B-aligned, conflict-benign

    const int t = threadIdx.x, lane = t & 63, w = t >> 6;
    const int l15 = lane & 15, l4 = lane >> 4;
    const int row0 = blockIdx.x * 64;

    f32x4 acc[4][2];
    {
        float4 b0 = *(const float4*)(bsum + (2 * w) * 16 + l4 * 4);
        float4 b1 = *(const float4*)(bsum + (2 * w + 1) * 16 + l4 * 4);
#pragma unroll
        for (int rt = 0; rt < 4; ++rt) {
            acc[rt][0] = f32x4{b0.x, b0.y, b0.z, b0.w};
            acc[rt][1] = f32x4{b1.x, b1.y, b1.z, b1.w};
        }
    }

    for (int seg = 0; seg < 4; ++seg) {
        __syncthreads();  // prior reads of As complete
        const ushort* srcbase = (seg < NR) ? (mean_b + (size_t)seg * NN * DH) : tb;
#pragma unroll
        for (int i = 0; i < 4; ++i) {
            int q = i * 256 + t;
            int r = q >> 4, c = q & 15;
            int node = row0 + r;
            uint4 v = make_uint4(0, 0, 0, 0);
            if (node < NN) v = *(const uint4*)(srcbase + (size_t)node * DH + c * 8);
            *(uint4*)(&As[r][c * 8]) = v;
        }
        __syncthreads();
        const ushort* wseg = Wp + (size_t)seg * 32768;
#pragma unroll
        for (int kc = 0; kc < 4; ++kc) {
            const ushort* wkc = wseg + kc * 8192;
            short8 bh0 = *(const short8*)(wkc + (2 * w) * 1024 + lane * 8);
            short8 bl0 = *(const short8*)(wkc + (2 * w) * 1024 + 512 + lane * 8);
            short8 bh1 = *(const short8*)(wkc + (2 * w + 1) * 1024 + lane * 8);
            short8 bl1 = *(const short8*)(wkc + (2 * w + 1) * 1024 + 512 + lane * 8);
#pragma unroll
            for (int rt = 0; rt < 4; ++rt) {
                short8 a = *(const short8*)(&As[rt * 16 + l15][kc * 32 + l4 * 8]);
                acc[rt][0] = __builtin_amdgcn_mfma_f32_16x16x32_bf16(bh0, a, acc[rt][0], 0, 0, 0);
                acc[rt][0] = __builtin_amdgcn_mfma_f32_16x16x32_bf16(bl0, a, acc[rt][0], 0, 0, 0);
                acc[rt][1] = __builtin_amdgcn_mfma_f32_16x16x32_bf16(bh1, a, acc[rt][1], 0, 0, 0);
                acc[rt][1] = __builtin_amdgcn_mfma_f32_16x16x32_bf16(bl1, a, acc[rt][1], 0, 0, 0);
            }
        }
    }

    if constexpr (!LAST) {
        ushort* hb = (ushort*)h_out;
#pragma unroll
        for (int rt = 0; rt < 4; ++rt) {
            int node = row0 + rt * 16 + l15;
            if (node < NN) {
#pragma unroll
                for (int j = 0; j < 2; ++j) {
                    int c0 = (2 * w + j) * 16 + l4 * 4;
                    uint2 o;
                    o.x = pack2(fmaxf(acc[rt][j][0], 0.f), fmaxf(acc[rt][j][1], 0.f));
                    o.y = pack2(fmaxf(acc[rt][j][2], 0.f), fmaxf(acc[rt][j][3], 0.f));
                    *(uint2*)(hb + (size_t)node * DH + c0) = o;
                }
            }
        }
    } else {
        __syncthreads();  // MFMA reads of As done before overwrite
#pragma unroll
        for (int rt = 0; rt < 4; ++rt) {
            int rl = rt * 16 + l15;
#pragma unroll
            for (int j = 0; j < 2; ++j) {
                int c0 = (2 * w + j) * 16 + l4 * 4;
                uint2 o;
                o.x = pack2(fmaxf(acc[rt][j][0], 0.f), fmaxf(acc[rt][j][1], 0.f));
                o.y = pack2(fmaxf(acc[rt][j][2], 0.f), fmaxf(acc[rt][j][3], 0.f));
                *(uint2*)(&As[rl][c0]) = o;
            }
        }
        __syncthreads();
        // out[64x32] = relu(h2) @ linW + linb; wave w owns rows w*16..w*16+15
        f32x4 acc2[2];
        {
            float4 c0 = *(const float4*)(linb + l4 * 4);
            float4 c1 = *(const float4*)(linb + 16 + l4 * 4);
            acc2[0] = f32x4{c0.x, c0.y, c0.z, c0.w};
            acc2[1] = f32x4{c1.x, c1.y, c1.z, c1.w};
        }
#pragma unroll
        for (int kc = 0; kc < 4; ++kc) {
            short8 a = *(const short8*)(&As[w * 16 + l15][kc * 32 + l4 * 8]);
#pragma unroll
            for (int j = 0; j < 2; ++j) {
                short8 bh = *(const short8*)(lWp + (kc * 2 + j) * 1024 + lane * 8);
                short8 bl = *(const short8*)(lWp + (kc * 2 + j) * 1024 + 512 + lane * 8);
                acc2[j] = __builtin_amdgcn_mfma_f32_16x16x32_bf16(bh, a, acc2[j], 0, 0, 0);
                acc2[j] = __builtin_amdgcn_mfma_f32_16x16x32_bf16(bl, a, acc2[j], 0, 0, 0);
            }
        }
        float* outp = (float*)h_out;
        int node = row0 + w * 16 + l15;
        if (node < NN) {
#pragma unroll
            for (int j = 0; j < 2; ++j) {
                *(f32x4*)(outp + (size_t)node * 32 + j * 16 + l4 * 4) = acc2[j];
            }
        }
    }
}

extern "C" void kernel_launch(void* const* d_in, const int* in_sizes, int n_in,
                              void* d_out, int out_size, void* d_ws, size_t ws_size,
                              hipStream_t stream) {
    const float* x = (const float*)d_in[0];
    const int* ei = (const int*)d_in[1];
    const float* Wn = (const float*)d_in[2];
    const float* Wr = (const float*)d_in[3];
    const float* bc = (const float*)d_in[4];
    const float* linW = (const float*)d_in[5];
    const float* linb = (const float*)d_in[6];
    float* out = (float*)d_out;

    char* p = (char*)d_ws;
    int* deg = (int*)p;      p += (size_t)NR * NN * 4;
    int* offs = (int*)p;     p += (size_t)NR * NN * 4;
    int* cur = (int*)p;      p += (size_t)NR * NN * 4;
    int* csr = (int*)p;      p += (size_t)NR * NE * 4;
    ushort* Wpack = (ushort*)p; p += (size_t)264 * 1024 * 2;  // 540 KB
    float* bsum = (float*)p; p += 4096;
    ushort* xb = (ushort*)p;  p += (size_t)NN * DH * 2;
    ushort* h1b = (ushort*)p; p += (size_t)NN * DH * 2;
    ushort* mean_b = (ushort*)p; p += (size_t)NR * NN * DH * 2;  // total ~74 MB

    hipMemsetAsync(deg, 0, (size_t)NR * NN * 4, stream);

    int eb = (NR * NE + 255) / 256;
    count_kernel<<<eb, 256, 0, stream>>>(ei, deg);
    scan_kernel<<<NR, 1024, 0, stream>>>(deg, offs, cur);
    fill_kernel<<<eb, 256, 0, stream>>>(ei, cur, csr);
    prep_kernel<<<66, 256, 0, stream>>>(Wn, Wr, linW, Wpack);
    bias_kernel<<<1, 256, 0, stream>>>(bc, bsum);
    conv_kernel<<<(NN * DH / 4 + 255) / 256, 256, 0, stream>>>(x, xb);

    int lb = (NN + 63) / 64;  // 782

    // layer 1
    aggr_kernel<<<(NR * NN * 64 + 255) / 256, 256, 0, stream>>>(xb, mean_b, csr, offs, deg);
    gemm_mfma<false><<<lb, 256, 0, stream>>>(xb, mean_b, h1b, Wpack, bsum,
                                             nullptr, nullptr);
    // layer 2
    aggr_kernel<<<(NR * NN * 64 + 255) / 256, 256, 0, stream>>>(h1b, mean_b, csr, offs, deg);
    gemm_mfma<true><<<lb, 256, 0, stream>>>(h1b, mean_b, out,
                                            Wpack + (size_t)128 * 1024, bsum + DH,
                                            Wpack + (size_t)256 * 1024, linb);
}